// Round 4
// baseline (603.573 us; speedup 1.0000x reference)
//
#include <hip/hip_runtime.h>

// GRU4Rec fused, round 4: K-SPLIT ACROSS 4 WAVES.
//
// Rounds 1-3 all produced VGPR_Count=108 regardless of attributes: the RA
// homes the 192 per-lane weight floats in AGPRs and inserts a copy per use
// (VALU-busy time 1.9x the instruction model). Fix: shrink the per-lane
// weight footprint to 48 floats (3 gate-rows x 16-wide K-chunk) so the live
// set (~80 VGPRs) fits ANY occupancy target with zero spill pressure.
//
// Scan: block=256 (4 waves) owns one batch row. Wave w covers k in
// [16w,16w+16). Per step: 16 readlane + 48 FMA -> 3 partials ->
// ds_write_b128 into a double-buffered slab -> ONE __syncthreads ->
// all waves redundantly sum 4x ds_read_b128 + gates, so h stays replicated
// per-wave for the next step's readlane broadcasts. Token prefetch 2 deep.
//
// Proj: same K-split; rotating combine wave stores P rows.
//
// Shapes: B=4096, T=200, H=64, V=100000. fp32; ints arrive as int32.

#define T_SEQ 200
#define HD 64
#define VOCAB 100000
#define CH 16   // K-chunk per wave
#define NW 4    // waves per block
#define RPB 16  // vocab rows per block (proj)

typedef float v16f __attribute__((ext_vector_type(16)));

__device__ __forceinline__ float bcast(float v, int lane) {
  return __int_as_float(__builtin_amdgcn_readlane(__float_as_int(v), lane));
}

__device__ __forceinline__ float fsigmoid(float x) {
  float e = __builtin_amdgcn_exp2f(x * -1.442695040888963f);
  return __builtin_amdgcn_rcpf(1.0f + e);
}

__device__ __forceinline__ float ftanh(float x) {
  float e = __builtin_amdgcn_exp2f(x * -2.885390081777927f);
  return fmaf(2.0f, __builtin_amdgcn_rcpf(1.0f + e), -1.0f);
}

// Wave w, lane i: 16-wide K-chunk of rows {i, 64+i, 128+i} of [192][64] W.
#define LOAD_W3CHUNK(W, w, i, wr, wz, wn)                                  \
  do {                                                                     \
    const float* base = (W) + CH * (w);                                    \
    wr = *reinterpret_cast<const v16f*>(base + (size_t)(i)*HD);            \
    wz = *reinterpret_cast<const v16f*>(base + (size_t)(HD + (i)) * HD);   \
    wn = *reinterpret_cast<const v16f*>(base + (size_t)(2 * HD + (i)) * HD);\
  } while (0)

// ---------------------------------------------------------------- phase 1
__global__ __launch_bounds__(256) void gru_proj_kernel(
    const float* __restrict__ emb, const float* __restrict__ W_ih,
    float* __restrict__ P) {
  __shared__ float4 slab[2][NW][HD];
  const int tid = threadIdx.x;
  const int w = tid >> 6;
  const int i = tid & 63;
  const int v0 = blockIdx.x * RPB;

  v16f wr, wz, wn;
  LOAD_W3CHUNK(W_ih, w, i, wr, wz, wn);

  // Lane i holds emb[v][16w + (i&15)]; lanes replicate 4x within the wave.
  float xv[RPB];
#pragma unroll
  for (int r = 0; r < RPB; ++r)
    xv[r] = emb[(size_t)(v0 + r) * HD + CH * w + (i & 15)];

#pragma unroll 4
  for (int r = 0; r < RPB; ++r) {
    float ar = 0.f, az = 0.f, an = 0.f;
#pragma unroll
    for (int j = 0; j < CH; ++j) {
      float xk = bcast(xv[r], j);  // lane j holds emb[v][16w+j]
      ar = fmaf(wr[j], xk, ar);
      az = fmaf(wz[j], xk, az);
      an = fmaf(wn[j], xk, an);
    }
    slab[r & 1][w][i] = make_float4(ar, az, an, 0.f);
    __syncthreads();
    if (w == (r & 3)) {  // rotating combine wave
      float4 a = slab[r & 1][0][i], b = slab[r & 1][1][i];
      float4 c = slab[r & 1][2][i], d = slab[r & 1][3][i];
      float* Pr = P + (size_t)(v0 + r) * (3 * HD);
      Pr[i] = (a.x + b.x) + (c.x + d.x);
      Pr[HD + i] = (a.y + b.y) + (c.y + d.y);
      Pr[2 * HD + i] = (a.z + b.z) + (c.z + d.z);
    }
  }
}

// ---------------------------------------------------------------- phase 2
__global__ __launch_bounds__(256) void gru_scan_kernel(
    const int* __restrict__ seq_token, const int* __restrict__ seq_pos,
    const float* __restrict__ P, const float* __restrict__ W_hh,
    float* __restrict__ out) {
  __shared__ float4 slab[2][NW][HD];
  const int tid = threadIdx.x;
  const int w = tid >> 6;
  const int i = tid & 63;
  const int b = blockIdx.x;

  int L = seq_pos[b];
  L = L < 1 ? 1 : (L > T_SEQ ? T_SEQ : L);

  v16f wr, wz, wn;
  LOAD_W3CHUNK(W_hh, w, i, wr, wz, wn);

  const int* tok = seq_token + (size_t)b * T_SEQ;

  int t0 = tok[0];
  const float* P0 = P + (size_t)t0 * (3 * HD);
  float pr = P0[i], pz = P0[HD + i], pn = P0[2 * HD + i];
  int tk1 = (L > 1) ? tok[1] : 0;

  float h = 0.f;
  for (int t = 0; t < L; ++t) {
    // Prefetch next P row (token already resident) and token t+2.
    float nr = 0.f, nz = 0.f, nn = 0.f;
    if (t + 1 < L) {
      const float* Pn = P + (size_t)tk1 * (3 * HD);
      nr = Pn[i]; nz = Pn[HD + i]; nn = Pn[2 * HD + i];
    }
    int tk2 = (t + 2 < L) ? tok[t + 2] : 0;

    // Partial gh over this wave's K-chunk: h[16w+j] via readlane broadcast.
    float ar = 0.f, az = 0.f, an = 0.f;
#pragma unroll
    for (int j = 0; j < CH; ++j) {
      float hk = bcast(h, CH * w + j);
      ar = fmaf(wr[j], hk, ar);
      az = fmaf(wz[j], hk, az);
      an = fmaf(wn[j], hk, an);
    }
    slab[t & 1][w][i] = make_float4(ar, az, an, 0.f);
    __syncthreads();

    // Redundant combine in every wave keeps h replicated in-register.
    float4 q0 = slab[t & 1][0][i], q1 = slab[t & 1][1][i];
    float4 q2 = slab[t & 1][2][i], q3 = slab[t & 1][3][i];
    float gr = (q0.x + q1.x) + (q2.x + q3.x);
    float gz = (q0.y + q1.y) + (q2.y + q3.y);
    float gn = (q0.z + q1.z) + (q2.z + q3.z);

    float r = fsigmoid(pr + gr);
    float z = fsigmoid(pz + gz);
    float n = ftanh(fmaf(r, gn, pn));
    h = fmaf(z, h - n, n);  // (1-z)*n + z*h

    pr = nr; pz = nz; pn = nn;
    tk1 = tk2;
  }

  if (w == 0) out[(size_t)b * HD + i] = h;
}

extern "C" void kernel_launch(void* const* d_in, const int* in_sizes, int n_in,
                              void* d_out, int out_size, void* d_ws, size_t ws_size,
                              hipStream_t stream) {
  const int* seq_token = (const int*)d_in[0];   // [B, T] int32
  const int* seq_pos   = (const int*)d_in[1];   // [B] int32
  const float* emb     = (const float*)d_in[2]; // [V, H]
  const float* W_ih    = (const float*)d_in[3]; // [3H, H]
  const float* W_hh    = (const float*)d_in[4]; // [3H, H]
  float* out = (float*)d_out;                   // [B, H]

  const int B = in_sizes[1];                    // 4096

  float* P = (float*)d_ws;                      // P[V][3H] = 76.8 MB

  gru_proj_kernel<<<(VOCAB + RPB - 1) / RPB, NW * 64, 0, stream>>>(emb, W_ih, P);
  gru_scan_kernel<<<B, NW * 64, 0, stream>>>(seq_token, seq_pos, P, W_hh, out);
}

// Round 5
// 424.511 us; speedup vs baseline: 1.4218x; 1.4218x over previous
//
#include <hip/hip_runtime.h>

// GRU4Rec fused, round 5.
//
// Lessons: (r1-r3) 192 fp32 weight floats/lane always get demoted
// (VGPR_Count=108, VALU time 2x model) regardless of attributes.
// (r4) K-split across waves puts a barrier in the serial chain: worse.
//
// This round: single wave per row (no barriers), but weights in PACKED FP16
// (96 VGPRs) consumed via the v_fma_mix_f32 pattern (fp32 accumulate), and
// the pre-projected token table P stored in fp16 (38.4 MB; L3-resident).
// Load balance: counting-sort rows by descending length; wave g runs sorted
// jobs {g, B-1-g} -> ~201 steps per wave regardless of draw.
//
// Shapes: B=4096, T=200, H=64, V=100000. Output fp32.

#define T_SEQ 200
#define HD 64
#define VOCAB 100000
#define RPB 16    // vocab rows per proj block
#define PROW 192  // halves per P row: [0,128) = (r,z) interleaved, [128,192) = n

typedef float v16f __attribute__((ext_vector_type(16)));
typedef _Float16 v16h __attribute__((ext_vector_type(16)));
typedef _Float16 h2v __attribute__((ext_vector_type(2)));

__device__ __forceinline__ float bcast(float v, int lane) {
  return __int_as_float(__builtin_amdgcn_readlane(__float_as_int(v), lane));
}

__device__ __forceinline__ float fsigmoid(float x) {
  float e = __builtin_amdgcn_exp2f(x * -1.442695040888963f);
  return __builtin_amdgcn_rcpf(1.0f + e);
}

__device__ __forceinline__ float ftanh(float x) {
  float e = __builtin_amdgcn_exp2f(x * -2.885390081777927f);
  return fmaf(2.0f, __builtin_amdgcn_rcpf(1.0f + e), -1.0f);
}

// Load one 64-wide fp32 row of W (row-major [192][64]) as 4 fp16 chunks.
#define LOAD_ROW_F16(W, row, c0, c1, c2, c3)                         \
  do {                                                               \
    const v16f* p_ = reinterpret_cast<const v16f*>((W) + (size_t)(row)*HD); \
    c0 = __builtin_convertvector(p_[0], v16h);                       \
    c1 = __builtin_convertvector(p_[1], v16h);                       \
    c2 = __builtin_convertvector(p_[2], v16h);                       \
    c3 = __builtin_convertvector(p_[3], v16h);                       \
  } while (0)

// One 16-wide K-chunk of the three gate dot-products. xk broadcast via
// readlane; (float)chunk[j] + fmaf -> v_fma_mix_f32 (fp16 src, fp32 acc).
#define GH_CHUNK(cr, cz, cn, src, base, ar, az, an)                  \
  do {                                                               \
    _Pragma("unroll")                                                \
    for (int j_ = 0; j_ < 16; ++j_) {                                \
      float xk_ = bcast((src), (base) + j_);                         \
      ar = fmaf((float)cr[j_], xk_, ar);                             \
      az = fmaf((float)cz[j_], xk_, az);                             \
      an = fmaf((float)cn[j_], xk_, an);                             \
    }                                                                \
  } while (0)

__device__ __forceinline__ unsigned pack_h2(float a, float b) {
  unsigned short lo = __builtin_bit_cast(unsigned short, (_Float16)a);
  unsigned short hi = __builtin_bit_cast(unsigned short, (_Float16)b);
  return (unsigned)lo | ((unsigned)hi << 16);
}

// --------------------------------------------------- length sort (1 block)
__global__ __launch_bounds__(256) void sort_kernel(
    const int* __restrict__ seq_pos, int* __restrict__ order, int B) {
  __shared__ int hist[T_SEQ + 1];
  __shared__ int off[T_SEQ + 1];
  const int tid = threadIdx.x;
  for (int l = tid; l <= T_SEQ; l += 256) hist[l] = 0;
  __syncthreads();
  for (int b = tid; b < B; b += 256) {
    int L = seq_pos[b]; L = L < 1 ? 1 : (L > T_SEQ ? T_SEQ : L);
    atomicAdd(&hist[L], 1);
  }
  __syncthreads();
  if (tid == 0) {
    int run = 0;
    for (int l = T_SEQ; l >= 1; --l) { off[l] = run; run += hist[l]; }
  }
  __syncthreads();
  for (int b = tid; b < B; b += 256) {
    int L = seq_pos[b]; L = L < 1 ? 1 : (L > T_SEQ ? T_SEQ : L);
    int pos = atomicAdd(&off[L], 1);
    order[pos] = b;  // descending length
  }
}

// --------------------------------------------------- phase 1: P = W_ih @ emb
__global__ __launch_bounds__(64) void gru_proj_kernel(
    const float* __restrict__ emb, const float* __restrict__ W_ih,
    _Float16* __restrict__ P16) {
  const int i = threadIdx.x;
  const int v0 = blockIdx.x * RPB;

  v16h r0, r1, r2, r3, z0, z1, z2, z3, n0, n1, n2, n3;
  LOAD_ROW_F16(W_ih, i, r0, r1, r2, r3);
  LOAD_ROW_F16(W_ih, HD + i, z0, z1, z2, z3);
  LOAD_ROW_F16(W_ih, 2 * HD + i, n0, n1, n2, n3);

  float x[RPB];
#pragma unroll
  for (int r = 0; r < RPB; ++r)
    x[r] = emb[(size_t)(v0 + r) * HD + i];  // lane i holds emb[v][i]

#pragma unroll 4
  for (int r = 0; r < RPB; ++r) {
    float ar = 0.f, az = 0.f, an = 0.f;
    GH_CHUNK(r0, z0, n0, x[r], 0, ar, az, an);
    GH_CHUNK(r1, z1, n1, x[r], 16, ar, az, an);
    GH_CHUNK(r2, z2, n2, x[r], 32, ar, az, an);
    GH_CHUNK(r3, z3, n3, x[r], 48, ar, az, an);

    _Float16* Prow = P16 + (size_t)(v0 + r) * PROW;
    reinterpret_cast<unsigned*>(Prow)[i] = pack_h2(ar, az);  // halves 2i,2i+1
    Prow[128 + i] = (_Float16)an;
  }
}

// --------------------------------------------------- phase 2: recurrent scan
__global__ __launch_bounds__(64) void gru_scan_kernel(
    const int* __restrict__ seq_token, const int* __restrict__ seq_pos,
    const _Float16* __restrict__ P16, const float* __restrict__ W_hh,
    float* __restrict__ out, const int* __restrict__ order, int use_order,
    int B) {
  const int i = threadIdx.x;
  const int g = blockIdx.x;

  v16h r0, r1, r2, r3, z0, z1, z2, z3, n0, n1, n2, n3;
  LOAD_ROW_F16(W_hh, i, r0, r1, r2, r3);
  LOAD_ROW_F16(W_hh, HD + i, z0, z1, z2, z3);
  LOAD_ROW_F16(W_hh, 2 * HD + i, n0, n1, n2, n3);

#pragma unroll 1
  for (int js = 0; js < 2; ++js) {
    const int j = js ? (B - 1 - g) : g;
    const int b = use_order ? order[j] : j;

    int L = seq_pos[b];
    L = L < 1 ? 1 : (L > T_SEQ ? T_SEQ : L);
    const int* tok = seq_token + (size_t)b * T_SEQ;

    int t0 = tok[0];
    const _Float16* Pr0 = P16 + (size_t)t0 * PROW;
    h2v rz0 = __builtin_bit_cast(h2v, reinterpret_cast<const unsigned*>(Pr0)[i]);
    float pr = (float)rz0[0], pz = (float)rz0[1];
    float pn = (float)Pr0[128 + i];
    int tk1 = (L > 1) ? tok[1] : 0;

    float h = 0.f;
    for (int t = 0; t < L; ++t) {
      // Prefetch next step's P row (token already resident) + token t+2.
      unsigned u_rz = 0;
      _Float16 u_n = (_Float16)0.f;
      if (t + 1 < L) {
        const _Float16* Pn = P16 + (size_t)tk1 * PROW;
        u_rz = reinterpret_cast<const unsigned*>(Pn)[i];
        u_n = Pn[128 + i];
      }
      int tk2 = (t + 2 < L) ? tok[t + 2] : 0;

      // gh = W_hh rows {i,64+i,128+i} . h ; h[k] broadcast via readlane.
      float ar0 = 0.f, az0 = 0.f, an0 = 0.f;
      float ar1 = 0.f, az1 = 0.f, an1 = 0.f;
      GH_CHUNK(r0, z0, n0, h, 0, ar0, az0, an0);
      GH_CHUNK(r1, z1, n1, h, 16, ar1, az1, an1);
      GH_CHUNK(r2, z2, n2, h, 32, ar0, az0, an0);
      GH_CHUNK(r3, z3, n3, h, 48, ar1, az1, an1);

      float r = fsigmoid(pr + ar0 + ar1);
      float z = fsigmoid(pz + az0 + az1);
      float n = ftanh(fmaf(r, an0 + an1, pn));
      h = fmaf(z, h - n, n);  // (1-z)*n + z*h

      h2v nrz = __builtin_bit_cast(h2v, u_rz);
      pr = (float)nrz[0];
      pz = (float)nrz[1];
      pn = (float)u_n;
      tk1 = tk2;
    }

    out[(size_t)b * HD + i] = h;
  }
}

extern "C" void kernel_launch(void* const* d_in, const int* in_sizes, int n_in,
                              void* d_out, int out_size, void* d_ws, size_t ws_size,
                              hipStream_t stream) {
  const int* seq_token = (const int*)d_in[0];   // [B, T] int32
  const int* seq_pos   = (const int*)d_in[1];   // [B] int32
  const float* emb     = (const float*)d_in[2]; // [V, H]
  const float* W_ih    = (const float*)d_in[3]; // [3H, H]
  const float* W_hh    = (const float*)d_in[4]; // [3H, H]
  float* out = (float*)d_out;                   // [B, H] fp32

  const int B = in_sizes[1];                    // 4096

  _Float16* P16 = (_Float16*)d_ws;              // 38.4 MB
  const size_t pbytes = ((size_t)VOCAB * PROW * 2 + 255) & ~(size_t)255;
  int* order = (int*)((char*)d_ws + pbytes);
  const int use_order = (ws_size >= pbytes + (size_t)B * 4) ? 1 : 0;

  if (use_order) sort_kernel<<<1, 256, 0, stream>>>(seq_pos, order, B);
  gru_proj_kernel<<<VOCAB / RPB, 64, 0, stream>>>(emb, W_ih, P16);
  gru_scan_kernel<<<B / 2, 64, 0, stream>>>(seq_token, seq_pos, P16, W_hh, out,
                                            order, use_order, B);
}